// Round 3
// baseline (370.591 us; speedup 1.0000x reference)
//
#include <hip/hip_runtime.h>

typedef unsigned int u32;
typedef unsigned char u8;
typedef int i32x4 __attribute__((ext_vector_type(4)));
typedef int i32x16 __attribute__((ext_vector_type(16)));

// Workspace layout:
//   [0, 589824)          Wm[tap=r*3+s][oc][ic]  i8  (+/-1 weights)
//   [589824, +27570176)  Xp[n][h'][w'][ic] i8, h',w' in [0,58) (zero halo),
//                        ic-byte pre-swizzled by ((w'&7)<<4); row stride 14848.
#define WM_OFF 0
#define XP_OFF 589824
#define XROW 14848   // 58*256

// ---------------------------------------------------------------------------
// Kernel 1: decode codebook -> i8 +/-1 weights, layout [tap][oc][ic].
// ---------------------------------------------------------------------------
__global__ __launch_bounds__(256) void pack_w_i8(const int* __restrict__ enc,
                                                 const float* __restrict__ cb,
                                                 char* __restrict__ wm) {
    int idx = blockIdx.x * 256 + threadIdx.x;       // 0..589823 = 9*256*256
    int i   = idx & 255;
    int o   = (idx >> 8) & 255;
    int pos = idx >> 16;                            // 0..8
    int f = o * 2304 + i * 9 + pos;                 // OIHW flat index
    int j = f / 12;
    int t = f - j * 12;
    float v = cb[enc[j] * 12 + t];
    wm[idx] = v < 0.f ? (char)-1 : (char)1;
}

// ---------------------------------------------------------------------------
// Kernel 2: binarize x to NHWC i8 with zero halo + w-keyed swizzle.
// R3: 512 threads (8 waves, 32 channels each), 16 loads in flight per thread.
// R2 version (4 waves, 64 ch, unroll 4) was ~170us: 16 latency-serialized
// rounds of 4 outstanding HBM loads. Now 2 rounds of 16.
// ---------------------------------------------------------------------------
__global__ __launch_bounds__(512) void pack_x_i8(const float* __restrict__ x,
                                                 u8* __restrict__ xp) {
    __shared__ __align__(16) u8 xl[14336];          // [w 0..55][256 ic] swizzled
    int hh = blockIdx.x;
    int n  = blockIdx.y;
    int t  = threadIdx.x;
    u8* dst = xp + (size_t)(n * 58 + hh) * XROW;
    uint4 z = make_uint4(0u, 0u, 0u, 0u);
    if (hh == 0 || hh == 57) {                      // zero halo rows
        for (int g = t; g < 928; g += 512) *(uint4*)(dst + g * 16) = z;
        return;
    }
    int h  = hh - 1;
    int wv = t >> 6, lane = t & 63;                 // wave wv: channels wv*32..+32
    if (lane < 56) {
        int w = lane;
        const float* xq = x + (size_t)(n * 256 + wv * 32) * 3136 + h * 56 + w;
        int sw = ((w + 1) & 7) << 4;                // swizzle key = w' = w+1
        u32 q[8];
#pragma unroll
        for (int b = 0; b < 8; ++b) q[b] = 0;
#pragma unroll
        for (int hf = 0; hf < 2; ++hf) {
            float v[16];
#pragma unroll
            for (int c = 0; c < 16; ++c) v[c] = xq[(size_t)(hf * 16 + c) * 3136];
#pragma unroll
            for (int c = 0; c < 16; ++c) {
                int cc = hf * 16 + c;
                q[cc >> 2] |= (v[c] < 0.f ? 0xFFu : 0x01u) << (8 * (cc & 3));
            }
        }
#pragma unroll
        for (int b = 0; b < 8; ++b)
            *(u32*)&xl[w * 256 + ((wv * 32 + b * 4) ^ sw)] = q[b];
    }
    __syncthreads();
    // row out: [w'=0 zeros][w'=1..56 from LDS][w'=57 zeros]
    for (int g = t; g < 928; g += 512) {
        uint4 v = z;
        if (g >= 16 && g < 912) v = *(const uint4*)&xl[(g - 16) * 16];
        *(uint4*)(dst + g * 16) = v;
    }
}

// ---------------------------------------------------------------------------
// Kernel 3: i8 MFMA conv. R3 re-block: 256 thr (4 waves) = 256 oc x 64 px
// (ONE output row). Wave ocg=wave covers 64 oc; all waves share the px range.
// X tile = 3 padded rows (44.5 KB contiguous in Xp) staged once; LDS 46 KB ->
// 3 blocks/CU; launch_bounds(256,3) -> VGPR cap 170 (64 acc + ~100 arch).
// K-loop reorder: kcL(2) outer, (r,s)(9), kc4(4) INNER. The 8 A-loads of one
// (r,s) batch-issue up front; weight line 128B covers kc4=0..3 -> 3/4 L1-hit
// (R2: every A-load was an L2 round-trip; MfmaUtil 16%, all stall).
// A-frag: lane row=oc=l&31, ic = kb = kc*32+(l>>5)*16 (+e). B-frag: col=px,
// same ic indexing. C/D: col=l&31 (px), row=(q&3)+8*(q>>2)+4*(l>>5) (oc).
// ---------------------------------------------------------------------------
__global__ __launch_bounds__(256, 3) void conv_mfma(const u8* __restrict__ xp,
                                                    const char* __restrict__ wm,
                                                    float* __restrict__ y) {
    __shared__ __align__(16) u8 xl[47104];   // 3*14848=44544 staged + read slack
    int t = threadIdx.x;
    int h = blockIdx.x;                      // 0..55
    int n = blockIdx.y;                      // 0..31
    const u8* src = xp + (size_t)(n * 58 + h) * XROW;   // padded rows h..h+2
    for (int g = t; g < 2784; g += 256)
        *(uint4*)&xl[g * 16] = *(const uint4*)(src + (size_t)g * 16);
    __syncthreads();

    int wave = t >> 6, lane = t & 63;
    int col  = lane & 31;
    int half = lane >> 5;
    int ocw  = wave * 64;

    i32x16 acc[2][2] = {};
    const char* wl = wm + (size_t)(ocw + col) * 256;
    int sw0 = ((col + 0) & 7) << 4;
    int sw1 = ((col + 1) & 7) << 4;
    int sw2 = ((col + 2) & 7) << 4;
    int cb0 = (col + 0) * 256;
    int cb1 = (col + 1) * 256;
    int cb2 = (col + 2) * 256;

#pragma unroll 1
    for (int kcL = 0; kcL < 2; ++kcL) {
        int kbL = kcL * 128 + half * 16;
#pragma unroll 1
        for (int r = 0; r < 3; ++r) {
            int rowb = r * XROW;
#pragma unroll
            for (int s = 0; s < 3; ++s) {
                const char* wt = wl + (size_t)(r * 3 + s) * 65536;
                int sw = (s == 0) ? sw0 : (s == 1 ? sw1 : sw2);
                int cb = rowb + ((s == 0) ? cb0 : (s == 1 ? cb1 : cb2));
                i32x4 a0[4], a1[4];
#pragma unroll
                for (int k4 = 0; k4 < 4; ++k4) {
                    int kb = kbL + k4 * 32;
                    a0[k4] = *(const i32x4*)(wt + kb);
                    a1[k4] = *(const i32x4*)(wt + 8192 + kb);
                }
#pragma unroll
                for (int k4 = 0; k4 < 4; ++k4) {
                    int ka = cb + ((kbL + k4 * 32) ^ sw);
                    i32x4 b0 = *(const i32x4*)&xl[ka];
                    i32x4 b1 = *(const i32x4*)&xl[ka + 8192];   // px +32, same swz
                    acc[0][0] = __builtin_amdgcn_mfma_i32_32x32x32_i8(a0[k4], b0, acc[0][0], 0, 0, 0);
                    acc[0][1] = __builtin_amdgcn_mfma_i32_32x32x32_i8(a0[k4], b1, acc[0][1], 0, 0, 0);
                    acc[1][0] = __builtin_amdgcn_mfma_i32_32x32x32_i8(a1[k4], b0, acc[1][0], 0, 0, 0);
                    acc[1][1] = __builtin_amdgcn_mfma_i32_32x32x32_i8(a1[k4], b1, acc[1][1], 0, 0, 0);
                }
            }
        }
    }

    float* yb = y + (size_t)n * 256 * 3136 + (size_t)h * 56;
#pragma unroll
    for (int at = 0; at < 2; ++at) {
#pragma unroll
        for (int bt = 0; bt < 2; ++bt) {
            int w = bt * 32 + col;
            if (w < 56) {
#pragma unroll
                for (int q = 0; q < 16; ++q) {
                    int oc = ocw + at * 32 + (q & 3) + 8 * (q >> 2) + 4 * half;
                    yb[(size_t)oc * 3136 + w] = (float)acc[at][bt][q];
                }
            }
        }
    }
}

extern "C" void kernel_launch(void* const* d_in, const int* in_sizes, int n_in,
                              void* d_out, int out_size, void* d_ws, size_t ws_size,
                              hipStream_t stream) {
    const float* x  = (const float*)d_in[0];
    // d_in[1] (latent weight) unused in the STE forward value.
    const float* cb = (const float*)d_in[2];
    const int* enc  = (const int*)d_in[3];
    float* y        = (float*)d_out;

    char* wmc = (char*)d_ws + WM_OFF;
    u8*   xpp = (u8*)d_ws + XP_OFF;

    hipLaunchKernelGGL(pack_w_i8, dim3(2304), dim3(256), 0, stream, enc, cb, wmc);
    hipLaunchKernelGGL(pack_x_i8, dim3(58, 32), dim3(512), 0, stream, x, xpp);
    hipLaunchKernelGGL(conv_mfma, dim3(56, 32), dim3(256), 0, stream, xpp, wmc, y);
}

// Round 4
// 283.343 us; speedup vs baseline: 1.3079x; 1.3079x over previous
//
#include <hip/hip_runtime.h>

typedef unsigned int u32;
typedef unsigned char u8;
typedef unsigned long long u64;
typedef int i32x4 __attribute__((ext_vector_type(4)));
typedef int i32x16 __attribute__((ext_vector_type(16)));

// Workspace layout (28.1 MB, same footprint as the proven R3 run):
//   [0, 589824)          Wm[step=tap*8+kc][oc][ic32] i8 (+/-1), step-region 8KB
//   [589824, +27557888)  Xp[n][h'][w'][ic] i8, h',w' in [0,58) zero halo,
//                        ic byte-index XOR-swizzled by ((w'&15)<<4); row 14848B
// Bitplanes bp (3.2 MB) live in d_out (y), consumed by expand_x BEFORE conv
// overwrites y. Stream-ordered => race-free; avoids growing ws past proven.
#define WM_OFF 0
#define XP_OFF 589824
#define XROW 14848   // 58*256

// ---------------------------------------------------------------------------
// Kernel 1: decode codebook -> i8 +/-1 weights, layout [tap*8+kc][oc][ic32].
// Per K-step the A-operand is ONE contiguous 8KB region (R3 post-mortem: the
// old [tap][oc][ic256] layout made every step touch 32KB of scattered lines
// -> L1 thrash -> serial L2 round-trips, MfmaUtil 14.5%).
// ---------------------------------------------------------------------------
__global__ __launch_bounds__(256) void pack_w_i8(const int* __restrict__ enc,
                                                 const float* __restrict__ cb,
                                                 char* __restrict__ wm) {
    int idx  = blockIdx.x * 256 + threadIdx.x;  // 0..589823
    int icin = idx & 31;
    int oc   = (idx >> 5) & 255;
    int step = idx >> 13;                        // 0..71 = tap*8+kc
    int tap  = step >> 3;
    int kc   = step & 7;
    int i = kc * 32 + icin;
    int f = oc * 2304 + i * 9 + tap;             // OIHW flat index
    int j = f / 12;
    int t = f - j * 12;
    float v = cb[enc[j] * 12 + t];
    wm[idx] = v < 0.f ? (char)-1 : (char)1;
}

// ---------------------------------------------------------------------------
// Kernel 2a: binarize x -> bitplanes. FULLY CONTIGUOUS streaming read (the
// R2/R3 pack_x read 224B chunks at 12.5KB channel stride and sat at ~0.7TB/s
// regardless of batching depth -> pattern-bound, not latency-bound).
// Each wave owns 64 consecutive u64 words = 16KB contiguous of x.
// bp[w] = ballot bits of x[w*64 + lane] < 0.  3136 = 49*64 so words never
// straddle channel planes: word = (n*256+ch)*49 + (px>>6), bit = px&63.
// ---------------------------------------------------------------------------
__global__ __launch_bounds__(256) void bin_bits(const float* __restrict__ x,
                                                u64* __restrict__ bp) {
    int gw   = blockIdx.x * 4 + (threadIdx.x >> 6);  // 0..6271
    int lane = threadIdx.x & 63;
    const float* xb = x + (size_t)gw * 4096 + lane;
#pragma unroll 1
    for (int k = 0; k < 8; ++k) {
        float v[8];
#pragma unroll
        for (int j = 0; j < 8; ++j) v[j] = xb[k * 512 + j * 64];
        u64 mine = 0;
#pragma unroll
        for (int j = 0; j < 8; ++j) {
            u64 m = __ballot(v[j] < 0.f);
            if (lane == j) mine = m;
        }
        if (lane < 8) bp[(size_t)gw * 64 + k * 8 + lane] = mine;
    }
}

// ---------------------------------------------------------------------------
// Kernel 2b: expand bitplanes -> swizzled Xp bytes. bp is 3.2MB (L2-hot).
// Block (hh, n), 256 thr: thread = (wseg 0..7, oct 0..31); holds the 2 u64
// words covering its row for its 8 channels in regs, emits one u64 (8 ic
// bytes) per w' position. Stores coalesce to 256B permuted blocks.
// ---------------------------------------------------------------------------
__global__ __launch_bounds__(256) void expand_x(const u64* __restrict__ bp,
                                                u8* __restrict__ xp) {
    int hh = blockIdx.x;                 // 0..57
    int n  = blockIdx.y;
    int t  = threadIdx.x;
    int oct  = t & 31;
    int wseg = t >> 5;                   // 0..7
    u8* dst = xp + (size_t)(n * 58 + hh) * XROW;
    if (hh == 0 || hh == 57) {           // zero halo rows
#pragma unroll
        for (int k = 0; k < 8; ++k) {
            int wq = wseg * 8 + k;
            if (wq < 58)
                *(u64*)(dst + wq * 256 + ((oct * 8) ^ ((wq & 15) << 4))) = 0ull;
        }
        return;
    }
    int h   = hh - 1;
    int pxr = h * 56;
    int w0  = pxr >> 6;
    int w1  = w0 + 1; if (w1 > 48) w1 = 48;
    u64 A[8], B[8];
    const u64* bq = bp + ((size_t)n * 256 + oct * 8) * 49;
#pragma unroll
    for (int j = 0; j < 8; ++j) A[j] = bq[j * 49 + w0];
#pragma unroll
    for (int j = 0; j < 8; ++j) B[j] = bq[j * 49 + w1];
#pragma unroll
    for (int k = 0; k < 8; ++k) {
        int wq = wseg * 8 + k;
        if (wq >= 58) break;
        u64 out = 0;
        if (wq >= 1 && wq <= 56) {
            int px  = pxr + wq - 1;
            bool s2 = (px >> 6) != w0;
            int bit = px & 63;
#pragma unroll
            for (int j = 0; j < 8; ++j) {
                u64 wv = s2 ? B[j] : A[j];
                out |= ((((wv >> bit) & 1ull) ? 0xFFull : 0x01ull)) << (8 * j);
            }
        }
        *(u64*)(dst + wq * 256 + ((oct * 8) ^ ((wq & 15) << 4))) = out;
    }
}

// ---------------------------------------------------------------------------
// Kernel 3: i8 MFMA conv. 512 thr, 8 waves = 256 oc x 128 px (2 output rows).
// Wave (ocg=wave&3, pxg=wave>>2) owns 64 oc x 64 px = 2x2 tiles of 32x32.
// X tile (4 padded rows, 59392B contiguous) staged to LDS once.
// K-loop: 72 steps; A walks Wm LINEARLY (wp += 8192) with explicit 1-step
// register prefetch -> MFMA waits on a 1-iter-old, L1-hit load (R3: every
// A-load was a serial L2 round-trip). Swizzle (w'&15)<<4: B-read conflicts
// 2-way max (free, m136). b1 = b0+8192 valid since 32 == 0 mod 16.
// C/D: col=l&31 (px), row=(q&3)+8*(q>>2)+4*(l>>5) (oc)  [HW-verified].
// ---------------------------------------------------------------------------
__global__ __launch_bounds__(512, 4) void conv_mfma(const u8* __restrict__ xp,
                                                    const char* __restrict__ wm,
                                                    float* __restrict__ y) {
    __shared__ __align__(16) u8 xl[61440];   // 4*14848 + slack for w'<=65 reads
    int t  = threadIdx.x;
    int n  = blockIdx.y;
    int h0 = blockIdx.x * 2;
    const u8* src = xp + (size_t)(n * 58 + h0) * XROW;   // padded rows h0..h0+3
    for (int g = t; g < 3712; g += 512)
        *(uint4*)&xl[g * 16] = *(const uint4*)(src + (size_t)g * 16);
    __syncthreads();

    int wave = t >> 6, lane = t & 63;
    int ocg  = wave & 3;
    int pxg  = wave >> 2;
    int col  = lane & 31;
    int half = lane >> 5;
    int ocw  = ocg * 64;

    i32x16 acc[2][2] = {};
    const char* wp = wm + (size_t)((ocw + col) * 32 + half * 16);
    i32x4 a0c = *(const i32x4*)wp;            // step 0 A-frags
    i32x4 a1c = *(const i32x4*)(wp + 1024);   // oc+32 -> +32*32B
    int h16 = half * 16;
    int sw0 = ((col + 0) & 15) << 4;
    int sw1 = ((col + 1) & 15) << 4;
    int sw2 = ((col + 2) & 15) << 4;
    int cb0 = (col + 0) * 256;
    int cb1 = (col + 1) * 256;
    int cb2 = (col + 2) * 256;

#pragma unroll 1
    for (int r = 0; r < 3; ++r) {
        int rowb = (pxg + r) * XROW;
#pragma unroll
        for (int s = 0; s < 3; ++s) {
            int sw    = (s == 0) ? sw0 : (s == 1 ? sw1 : sw2);
            int cbase = rowb + ((s == 0) ? cb0 : (s == 1 ? cb1 : cb2));
#pragma unroll 1
            for (int kc = 0; kc < 8; ++kc) {
                wp += 8192;                              // next step (linear!)
                i32x4 a0n = *(const i32x4*)wp;           // prefetch (last iter
                i32x4 a1n = *(const i32x4*)(wp + 1024);  // overreads into Xp: ok)
                int ba = cbase + ((kc * 32 + h16) ^ sw);
                i32x4 b0 = *(const i32x4*)&xl[ba];
                i32x4 b1 = *(const i32x4*)&xl[ba + 8192];   // w'+32, same swz
                acc[0][0] = __builtin_amdgcn_mfma_i32_32x32x32_i8(a0c, b0, acc[0][0], 0, 0, 0);
                acc[0][1] = __builtin_amdgcn_mfma_i32_32x32x32_i8(a0c, b1, acc[0][1], 0, 0, 0);
                acc[1][0] = __builtin_amdgcn_mfma_i32_32x32x32_i8(a1c, b0, acc[1][0], 0, 0, 0);
                acc[1][1] = __builtin_amdgcn_mfma_i32_32x32x32_i8(a1c, b1, acc[1][1], 0, 0, 0);
                a0c = a0n; a1c = a1n;
            }
        }
    }

    int h = h0 + pxg;
    float* yb = y + (size_t)n * 256 * 3136 + (size_t)h * 56;
#pragma unroll
    for (int at = 0; at < 2; ++at) {
#pragma unroll
        for (int bt = 0; bt < 2; ++bt) {
            int w = bt * 32 + col;
            if (w < 56) {
#pragma unroll
                for (int q = 0; q < 16; ++q) {
                    int oc = ocw + at * 32 + (q & 3) + 8 * (q >> 2) + 4 * half;
                    yb[(size_t)oc * 3136 + w] = (float)acc[at][bt][q];
                }
            }
        }
    }
}

extern "C" void kernel_launch(void* const* d_in, const int* in_sizes, int n_in,
                              void* d_out, int out_size, void* d_ws, size_t ws_size,
                              hipStream_t stream) {
    const float* x  = (const float*)d_in[0];
    // d_in[1] (latent weight) unused in the STE forward value.
    const float* cb = (const float*)d_in[2];
    const int* enc  = (const int*)d_in[3];
    float* y        = (float*)d_out;

    char* wmc = (char*)d_ws + WM_OFF;
    u8*   xpp = (u8*)d_ws + XP_OFF;
    u64*  bp  = (u64*)d_out;   // scratch inside y: consumed by expand_x before
                               // conv_mfma overwrites y (stream-ordered)

    hipLaunchKernelGGL(pack_w_i8, dim3(2304), dim3(256), 0, stream, enc, cb, wmc);
    hipLaunchKernelGGL(bin_bits, dim3(1568), dim3(256), 0, stream, x, bp);
    hipLaunchKernelGGL(expand_x, dim3(58, 32), dim3(256), 0, stream, bp, xpp);
    hipLaunchKernelGGL(conv_mfma, dim3(28, 32), dim3(512), 0, stream, xpp, wmc, y);
}

// Round 5
// 263.512 us; speedup vs baseline: 1.4064x; 1.0753x over previous
//
#include <hip/hip_runtime.h>

typedef unsigned int u32;
typedef unsigned char u8;
typedef unsigned long long u64;
typedef int i32x4 __attribute__((ext_vector_type(4)));
typedef int i32x16 __attribute__((ext_vector_type(16)));

// Workspace layout (3.8 MB used):
//   [0, 589824)          Wm[step=tap*8+kc][oc][ic32] i8 (+/-1), 8KB per step
//   [589824, +3211264)   bp bitplanes: bp[(n*256+ch)*49 + (px>>6)], bit px&63
// Xp is GONE (R4 post-mortem: non-conv time invariant ~190us across 3
// implementations -> the materialize-Xp structure itself was the cost).
// conv expands bitplanes -> swizzled LDS tile in its prologue.
#define WM_OFF 0
#define BP_OFF 589824

// ---------------------------------------------------------------------------
// Kernel 1: prep = pack_w (blocks 0..2303) + bin_bits (blocks 2304..3871).
// pack_w: decode codebook -> i8 +/-1 weights, [tap*8+kc][oc][ic32] so each
// K-step's A-operand is one contiguous 8KB region (proven R4: lin walk).
// bin_bits: fully-contiguous stream of x -> sign bitplanes via ballot.
// 3136 = 49*64, so u64 words never straddle channel planes.
// ---------------------------------------------------------------------------
__global__ __launch_bounds__(256) void prep(const int* __restrict__ enc,
                                            const float* __restrict__ cb,
                                            char* __restrict__ wm,
                                            const float* __restrict__ x,
                                            u64* __restrict__ bp) {
    int bid = blockIdx.x;
    if (bid < 2304) {
        int idx  = bid * 256 + threadIdx.x;          // 0..589823
        int icin = idx & 31;
        int oc   = (idx >> 5) & 255;
        int step = idx >> 13;                        // 0..71 = tap*8+kc
        int tap  = step >> 3;
        int kc   = step & 7;
        int i = kc * 32 + icin;
        int f = oc * 2304 + i * 9 + tap;             // OIHW flat index
        int j = f / 12;
        int t = f - j * 12;
        float v = cb[enc[j] * 12 + t];
        wm[idx] = v < 0.f ? (char)-1 : (char)1;
    } else {
        int gw   = (bid - 2304) * 4 + (threadIdx.x >> 6);  // 0..6271
        int lane = threadIdx.x & 63;
        const float* xb = x + (size_t)gw * 4096 + lane;
#pragma unroll 1
        for (int k = 0; k < 8; ++k) {
            float v[8];
#pragma unroll
            for (int j = 0; j < 8; ++j) v[j] = xb[k * 512 + j * 64];
            u64 mine = 0;
#pragma unroll
            for (int j = 0; j < 8; ++j) {
                u64 m = __ballot(v[j] < 0.f);
                if (lane == j) mine = m;
            }
            if (lane < 8) bp[(size_t)gw * 64 + k * 8 + lane] = mine;
        }
    }
}

// ---------------------------------------------------------------------------
// Kernel 2: i8 MFMA conv, bitplane-fed. 512 thr, 8 waves = 256 oc x 128 px
// (2 output rows). Prologue expands bp (L2-hot, 16 x 8B gathers/thread) into
// the swizzled LDS X-tile [rr 0..3][w' 0..57][ic^((w'&15)<<4)] — replaces the
// old global Xp (27.5MB write + 31.6MB HBM re-read eliminated).
// K-loop: 72 linear steps, DEPTH-2 register A-prefetch (R4 was depth-1 ->
// every step waited ~L2 latency; MfmaUtil 32%). B from LDS, conflict-free.
// C/D: col=l&31 (px), row=(q&3)+8*(q>>2)+4*(l>>5) (oc)  [HW-verified].
// Tail prefetches (steps 72,73) overread into bp region: valid ws, unused.
// ---------------------------------------------------------------------------
__global__ __launch_bounds__(512, 4) void conv_mfma(const u64* __restrict__ bp,
                                                    const char* __restrict__ wm,
                                                    float* __restrict__ y) {
    __shared__ __align__(16) u8 xl[61440];   // 4*14848 staged + read slack
    int t  = threadIdx.x;
    int n  = blockIdx.y;
    int h0 = blockIdx.x * 2;

    {   // ---- expand bitplanes -> LDS tile (4 padded rows h0..h0+3) ----
        int oct  = t & 31;                   // ic octet: channels oct*8..+8
        int wseg = (t >> 5) & 3;             // w' = wseg + 4k
        int rr   = t >> 7;                   // padded row index 0..3
        int h    = h0 + rr - 1;
        bool rowv = (h >= 0) && (h <= 55);
        int w0c = rowv ? ((h * 56) >> 6) : 0;
        int w1c = w0c + 1; if (w1c > 48) w1c = 48;
        const u64* bq = bp + ((size_t)n * 256 + oct * 8) * 49;
        u64 A[8], B[8];
#pragma unroll
        for (int j = 0; j < 8; ++j) A[j] = bq[j * 49 + w0c];
#pragma unroll
        for (int j = 0; j < 8; ++j) B[j] = bq[j * 49 + w1c];
        u8* xr = xl + rr * 14848;
#pragma unroll 1
        for (int k = 0; k < 15; ++k) {
            int wq = wseg + k * 4;
            if (wq >= 58) break;
            u64 out = 0;
            if (rowv && wq >= 1 && wq <= 56) {
                int px  = h * 56 + wq - 1;
                int bit = px & 63;
                bool s2 = (px >> 6) != w0c;
#pragma unroll
                for (int j = 0; j < 8; ++j) {
                    u64 wv = s2 ? B[j] : A[j];
                    out |= (((wv >> bit) & 1ull) ? 0xFFull : 0x01ull) << (8 * j);
                }
            }
            *(u64*)(xr + wq * 256 + ((oct * 8) ^ ((wq & 15) << 4))) = out;
        }
    }
    __syncthreads();

    int wave = t >> 6, lane = t & 63;
    int ocg  = wave & 3;
    int pxg  = wave >> 2;
    int col  = lane & 31;
    int half = lane >> 5;
    int ocw  = ocg * 64;

    i32x16 acc[2][2] = {};
    const char* wp = wm + (size_t)((ocw + col) * 32 + half * 16);
    i32x4 c0 = *(const i32x4*)wp;             // step 0
    i32x4 c1 = *(const i32x4*)(wp + 1024);    // oc+32
    i32x4 n0 = *(const i32x4*)(wp + 8192);    // step 1
    i32x4 n1 = *(const i32x4*)(wp + 8192 + 1024);
    wp += 16384;                              // points at step 2
    int h16 = half * 16;
    int sw0 = ((col + 0) & 15) << 4;
    int sw1 = ((col + 1) & 15) << 4;
    int sw2 = ((col + 2) & 15) << 4;
    int cb0 = (col + 0) * 256;
    int cb1 = (col + 1) * 256;
    int cb2 = (col + 2) * 256;

#pragma unroll 1
    for (int r = 0; r < 3; ++r) {
        int rowb = (pxg + r) * 14848;
#pragma unroll
        for (int s = 0; s < 3; ++s) {
            int sw    = (s == 0) ? sw0 : (s == 1 ? sw1 : sw2);
            int cbase = rowb + ((s == 0) ? cb0 : (s == 1 ? cb1 : cb2));
#pragma unroll 1
            for (int kc = 0; kc < 8; ++kc) {
                i32x4 t0 = *(const i32x4*)wp;           // prefetch step+2
                i32x4 t1 = *(const i32x4*)(wp + 1024);
                wp += 8192;
                int ba = cbase + ((kc * 32 + h16) ^ sw);
                i32x4 b0 = *(const i32x4*)&xl[ba];
                i32x4 b1 = *(const i32x4*)&xl[ba + 8192];   // w'+32, same swz
                acc[0][0] = __builtin_amdgcn_mfma_i32_32x32x32_i8(c0, b0, acc[0][0], 0, 0, 0);
                acc[0][1] = __builtin_amdgcn_mfma_i32_32x32x32_i8(c0, b1, acc[0][1], 0, 0, 0);
                acc[1][0] = __builtin_amdgcn_mfma_i32_32x32x32_i8(c1, b0, acc[1][0], 0, 0, 0);
                acc[1][1] = __builtin_amdgcn_mfma_i32_32x32x32_i8(c1, b1, acc[1][1], 0, 0, 0);
                c0 = n0; c1 = n1; n0 = t0; n1 = t1;     // rotate (static)
            }
        }
    }

    int h = h0 + pxg;
    float* yb = y + (size_t)n * 256 * 3136 + (size_t)h * 56;
#pragma unroll
    for (int at = 0; at < 2; ++at) {
#pragma unroll
        for (int bt = 0; bt < 2; ++bt) {
            int w = bt * 32 + col;
            if (w < 56) {
#pragma unroll
                for (int q = 0; q < 16; ++q) {
                    int oc = ocw + at * 32 + (q & 3) + 8 * (q >> 2) + 4 * half;
                    yb[(size_t)oc * 3136 + w] = (float)acc[at][bt][q];
                }
            }
        }
    }
}

extern "C" void kernel_launch(void* const* d_in, const int* in_sizes, int n_in,
                              void* d_out, int out_size, void* d_ws, size_t ws_size,
                              hipStream_t stream) {
    const float* x  = (const float*)d_in[0];
    // d_in[1] (latent weight) unused in the STE forward value.
    const float* cb = (const float*)d_in[2];
    const int* enc  = (const int*)d_in[3];
    float* y        = (float*)d_out;

    char* wmc = (char*)d_ws + WM_OFF;
    u64*  bp  = (u64*)((char*)d_ws + BP_OFF);

    hipLaunchKernelGGL(prep, dim3(3872), dim3(256), 0, stream, enc, cb, wmc, x, bp);
    hipLaunchKernelGGL(conv_mfma, dim3(28, 32), dim3(512), 0, stream, bp, wmc, y);
}